// Round 1
// baseline (226.662 us; speedup 1.0000x reference)
//
#include <hip/hip_runtime.h>
#include <stdint.h>

#define B_ 2
#define S_ 2048
#define E_ 1024
#define H_ 16
#define D_ 64
#define M_ (B_*S_)
#define PROJ_ ((size_t)M_*E_)
#define HALF_W 128

typedef float    f32x4 __attribute__((ext_vector_type(4)));
typedef short    s16x4 __attribute__((ext_vector_type(4)));
typedef short    s16x8 __attribute__((ext_vector_type(8)));
typedef __bf16   bf16x8 __attribute__((ext_vector_type(8)));
typedef _Float16 f16x8 __attribute__((ext_vector_type(8)));
typedef unsigned int u32x4 __attribute__((ext_vector_type(4)));

typedef const __attribute__((address_space(1))) void* gas_t;
typedef __attribute__((address_space(3))) void*       las_t;

__device__ __forceinline__ void gl16(const void* g, void* l) {
    __builtin_amdgcn_global_load_lds((gas_t)g, (las_t)l, 16, 0, 0);
}

__device__ __forceinline__ f32x4 MFMA(bf16x8 a, bf16x8 b, f32x4 c) {
    return __builtin_amdgcn_mfma_f32_16x16x32_bf16(a, b, c, 0, 0, 0);
}
__device__ __forceinline__ f32x4 MFMAH(f16x8 a, f16x8 b, f32x4 c) {
    return __builtin_amdgcn_mfma_f32_16x16x32_f16(a, b, c, 0, 0, 0);
}

// raw v_exp_f32 — bypasses __ocml_exp2_f32's fixup path (args bounded here)
__device__ __forceinline__ float fexp2(float x) {
    return __builtin_amdgcn_exp2f(x);
}

__device__ __forceinline__ unsigned short f2bf(float f) {
    union { float f; unsigned int u; } x; x.f = f;
    unsigned int u = x.u + 0x7FFFu + ((x.u >> 16) & 1u);
    return (unsigned short)(u >> 16);
}

__device__ __forceinline__ s16x8 cvt8(f32x4 a, f32x4 b) {
    s16x8 h;
    h[0]=(short)f2bf(a[0]); h[1]=(short)f2bf(a[1]); h[2]=(short)f2bf(a[2]); h[3]=(short)f2bf(a[3]);
    h[4]=(short)f2bf(b[0]); h[5]=(short)f2bf(b[1]); h[6]=(short)f2bf(b[2]); h[7]=(short)f2bf(b[3]);
    return h;
}

// ---------------------------------------------------------------------------
// Kernel 0: fp32 -> bf16 converts (X inputs; W matrices when ws allows).
// ---------------------------------------------------------------------------
__global__ __launch_bounds__(256) void cvt_kernel(
    const float* __restrict__ q, const float* __restrict__ k, const float* __restrict__ v,
    const float* __restrict__ Wq, const float* __restrict__ Wk,
    const float* __restrict__ Wv, const float* __restrict__ Wo,
    unsigned short* __restrict__ xq, unsigned short* __restrict__ xk,
    unsigned short* __restrict__ xv, unsigned short* __restrict__ wbf)
{
    const int z = blockIdx.y;
    if (z >= 3 && blockIdx.x >= 512) return;
    const float* src; unsigned short* dst;
    switch (z) {
        case 0: src = q;  dst = xq; break;
        case 1: src = k;  dst = xk; break;
        case 2: src = v;  dst = xv; break;
        case 3: src = Wq; dst = wbf; break;
        case 4: src = Wk; dst = wbf + (size_t)E_*E_; break;
        case 5: src = Wv; dst = wbf + 2*(size_t)E_*E_; break;
        default: src = Wo; dst = wbf + 3*(size_t)E_*E_; break;
    }
    size_t i = ((size_t)blockIdx.x * 256 + threadIdx.x) * 8;
    f32x4 a = *(const f32x4*)(src + i);
    f32x4 c = *(const f32x4*)(src + i + 4);
    *(s16x8*)(dst + i) = cvt8(a, c);
}

// ---------------------------------------------------------------------------
// Kernel 1: QKV projections, operand-swapped (A=W rows, B=X rows).
// 128x128 tile, BK=32, LDS dbuf async staging, 1 barrier/step.
// K pre-scaled by 0.125*log2(e). V stored f16 in blocked (bh,kb,d,slot)
// layout. grid=(8,32,3), block=256.  (round-10 config: best measured)
// ---------------------------------------------------------------------------
__global__ __launch_bounds__(256, 3) void qkv_kernel(
    const unsigned short* __restrict__ xq, const unsigned short* __restrict__ xk,
    const unsigned short* __restrict__ xv,
    const unsigned short* __restrict__ wbf,
    const float* __restrict__ Wq, const float* __restrict__ Wk, const float* __restrict__ Wv,
    const float* __restrict__ bq, const float* __restrict__ bk, const float* __restrict__ bv,
    unsigned short* __restrict__ qkvout)
{
    const int z = blockIdx.z;
    const unsigned short* X  = (z==0) ? xq : (z==1) ? xk : xv;
    const float*          Wf = (z==0) ? Wq : (z==1) ? Wk : Wv;
    const float*        bias = (z==0) ? bq : (z==1) ? bk : bv;
    const unsigned short* Wb = wbf ? (wbf + (size_t)z * E_ * E_) : nullptr;
    unsigned short* dst = qkvout + (size_t)z * PROJ_;

    __shared__ __align__(16) unsigned short As[2][128 * 32];   // W tile
    __shared__ __align__(16) unsigned short Bs[2][128 * 32];   // X tile

    const int t = threadIdx.x;
    const int lane = t & 63, w = t >> 6;
    const int quad = lane >> 4, l16 = lane & 15;
    const int wo = (w & 1) * 64, wsb = (w >> 1) * 64;
    const int oBase = blockIdx.x * 128, sBase = blockIdx.y * 128;

    const int r0 = t >> 2;
    const int c4 = (t & 3) ^ (r0 & 3);
    const unsigned short* gX  = X + (size_t)(sBase + r0) * E_ + c4 * 8;
    const unsigned short* gWb = Wb ? Wb + (size_t)(oBase + r0) * E_ + c4 * 8 : nullptr;
    const float*          gWf = Wf + (size_t)(oBase + r0) * E_ + c4 * 8;

    f32x4 acc[4][4] = {};   // [io][is]

    auto issue = [&](int kk, int pb) {
        unsigned short* dB = &Bs[pb][(size_t)w * 512];
        gl16(gX + kk, dB);
        gl16(gX + (size_t)64 * E_ + kk, dB + 2048);
        if (gWb) {
            unsigned short* dA = &As[pb][(size_t)w * 512];
            gl16(gWb + kk, dA);
            gl16(gWb + (size_t)64 * E_ + kk, dA + 2048);
        } else {
            const float* gp0 = gWf + kk;
            const float* gp1 = gWf + (size_t)64 * E_ + kk;
            f32x4 a0 = *(const f32x4*)gp0, a1 = *(const f32x4*)(gp0 + 4);
            f32x4 b0 = *(const f32x4*)gp1, b1 = *(const f32x4*)(gp1 + 4);
            *(s16x8*)&As[pb][(size_t)r0 * 32 + (t & 3) * 8]        = cvt8(a0, a1);
            *(s16x8*)&As[pb][(size_t)(r0 + 64) * 32 + (t & 3) * 8] = cvt8(b0, b1);
        }
    };

    issue(0, 0);
    __syncthreads();

    for (int s = 0; s < 32; s++) {
        const int pb = s & 1;
        if (s < 31) issue((s + 1) * 32, pb ^ 1);

        bf16x8 af[4], bfr[4];
        #pragma unroll
        for (int io = 0; io < 4; io++) {
            int r = wo + io * 16 + l16;
            af[io] = *(const bf16x8*)&As[pb][(size_t)r * 32 + ((quad ^ (l16 & 3)) * 8)];
        }
        #pragma unroll
        for (int is = 0; is < 4; is++) {
            int r = wsb + is * 16 + l16;
            bfr[is] = *(const bf16x8*)&Bs[pb][(size_t)r * 32 + ((quad ^ (l16 & 3)) * 8)];
        }
        #pragma unroll
        for (int io = 0; io < 4; io++)
            #pragma unroll
            for (int is = 0; is < 4; is++)
                acc[io][is] = MFMA(af[io], bfr[is], acc[io][is]);
        __syncthreads();
    }

    const float KSCL = 0.1803368801111204f;   // 0.125 * log2(e)
    #pragma unroll
    for (int is = 0; is < 4; is++) {
        int sg = sBase + wsb + is * 16 + l16;     // b*S + s
        int b = sg >> 11, sg2 = sg & 2047;
        int k6 = sg2 & 63;
        int slot = ((k6 >> 5) & 1) * 32 + ((k6 >> 2) & 3) * 8
                 + ((k6 >> 4) & 1) * 4 + (k6 & 3);
        #pragma unroll
        for (int io = 0; io < 4; io++) {
            int ocol0 = oBase + wo + io * 16 + quad * 4;
            f32x4 bias4 = *(const f32x4*)&bias[ocol0];
            int h = ocol0 >> 6, d0 = ocol0 & 63;
            size_t base = ((size_t)(b * H_ + h)) * ((size_t)S_ * D_);
            if (z == 0) {
                s16x4 h4;
                #pragma unroll
                for (int r = 0; r < 4; r++) h4[r] = (short)f2bf(acc[io][is][r] + bias4[r]);
                *(s16x4*)&dst[base + (size_t)sg2 * D_ + d0] = h4;
            } else if (z == 1) {
                s16x4 h4;
                #pragma unroll
                for (int r = 0; r < 4; r++)
                    h4[r] = (short)f2bf((acc[io][is][r] + bias4[r]) * KSCL);
                *(s16x4*)&dst[base + (size_t)sg2 * D_ + d0] = h4;
            } else {
                size_t vb = base + (size_t)(sg2 >> 6) * 4096 + (size_t)d0 * 64 + slot;
                #pragma unroll
                for (int r = 0; r < 4; r++) {
                    _Float16 hv = (_Float16)(acc[io][is][r] + bias4[r]);
                    dst[vb + (size_t)r * 64] = __builtin_bit_cast(unsigned short, hv);
                }
            }
        }
    }
}

// ---------------------------------------------------------------------------
// Kernel 2: fused attention. grid=(32 bh, 16 qtile) — bh on x so XCD=bh%8:
// each XCD serves 4 heads -> K/V working set ~2MB fits its L2.
// block=256 = 4 waves x 32 q rows (128-q tile): each K/V LDS fragment read
// feeds TWO q-groups -> LDS read bytes/FLOP halved vs 16 q/wave (was
// 43 TB/s = 62% of LDS ceiling while MfmaUtil only 32% -> LDS-BW bound).
// Additive mask folded into MFMA C-init (0 / log2e / per-elem cndmask on
// boundary tiles) -> single accumulator set, no epilogue combine, no
// divergent exp path. LDS dbuf, 1 barrier/tile, ones-MFMA denominator,
// f16 P/V, raw v_exp_f32.
// ---------------------------------------------------------------------------
__global__ __launch_bounds__(256, 2) void attn_kernel(
    const unsigned short* __restrict__ qkvout, unsigned short* __restrict__ attnout)
{
    const int bh = blockIdx.x, b = bh >> 4, h = bh & 15;
    const int qbase = blockIdx.y * 128;
    const int t = threadIdx.x, w = t >> 6, lane = t & 63;
    const int quad = lane >> 4, l16 = lane & 15;

    const unsigned short* qgp = qkvout + (size_t)bh * (S_ * D_);
    const unsigned short* kg = qkvout + PROJ_ + (size_t)bh * (S_ * D_);
    const unsigned short* vT = qkvout + 2 * PROJ_ + (size_t)bh * (S_ * D_);

    __shared__ __align__(16) unsigned short Ks [2][64 * 64];
    __shared__ __align__(16) unsigned short VTs[2][64 * 64];

    const int qw = qbase + w * 32;          // wave's first q row
    bf16x8 aq[2][2];
    #pragma unroll
    for (int qg = 0; qg < 2; qg++) {
        int qi = qw + qg * 16 + l16;
        aq[qg][0] = *(const bf16x8*)&qgp[(size_t)qi * 64 + quad * 8];
        aq[qg][1] = *(const bf16x8*)&qgp[(size_t)qi * 64 + 32 + quad * 8];
    }

    f32x4 O[2][4] = {};     // [qg][dt]
    f32x4 Sd[2] = {};       // softmax denominators

    const int r0 = t >> 3;
    const int ch = ((t & 7) ^ (r0 & 7)) * 8;

    f16x8 onesv;
    #pragma unroll
    for (int j = 0; j < 8; j++) onesv[j] = (_Float16)1.0f;

    const float LOG2E = 1.44269504089f;
    const f32x4 one4 = {LOG2E, LOG2E, LOG2E, LOG2E};
    const f32x4 zero4 = {};

    auto issue = [&](int kt, int pb) {
        unsigned short* dK = &Ks [pb][(size_t)w * 512];
        unsigned short* dV = &VTs[pb][(size_t)w * 512];
        gl16(kg + (size_t)(kt + r0) * 64 + ch,      dK);
        gl16(kg + (size_t)(kt + r0 + 32) * 64 + ch, dK + 2048);
        gl16(vT + (size_t)(kt + r0) * 64 + ch,      dV);
        gl16(vT + (size_t)(kt + r0 + 32) * 64 + ch, dV + 2048);
    };

    issue(0, 0);
    __syncthreads();

    #pragma unroll 2
    for (int s = 0; s < 32; s++) {
        const int pb = s & 1;
        const int kt = s * 64;
        if (s < 31) issue(kt + 64, pb ^ 1);

        // tile-uniform mask class per 16-q group: q in [Q0,Q0+16), j in [kt,kt+64)
        // di = q-j in [d-63, d+15], d = Q0-kt (multiple of 16).
        // all |di|<=128 -> cls0 (add 0); all |di|>128 -> cls1 (add 1*log2e); else cls2
        int cls[2];
        #pragma unroll
        for (int qg = 0; qg < 2; qg++) {
            int d = qw + qg * 16 - kt;
            cls[qg] = (d >= -64 && d <= 112) ? 0 : ((d >= 192 || d <= -144) ? 1 : 2);
        }

        const int sw = l16 & 7;
        u32x4 up[2][2];
        #pragma unroll
        for (int sub = 0; sub < 4; sub++) {
            int row = sub * 16 + l16;
            bf16x8 bk0 = *(const bf16x8*)&Ks[pb][(size_t)row * 64 + ((quad ^ sw) * 8)];
            bf16x8 bk1 = *(const bf16x8*)&Ks[pb][(size_t)row * 64 + (((4 + quad) ^ sw) * 8)];
            #pragma unroll
            for (int qg = 0; qg < 2; qg++) {
                f32x4 ci;
                if (cls[qg] == 0) {
                    ci = zero4;
                } else if (cls[qg] == 1) {
                    ci = one4;
                } else {
                    int jb = kt + sub * 16 + quad * 4;
                    int qi = qw + qg * 16 + l16;
                    #pragma unroll
                    for (int r = 0; r < 4; r++) {
                        int di = qi - (jb + r); di = di < 0 ? -di : di;
                        ci[r] = (di <= HALF_W) ? 0.f : LOG2E;
                    }
                }
                f32x4 zz = MFMA(bk0, aq[qg][0], ci);
                zz = MFMA(bk1, aq[qg][1], zz);
                float p0 = fexp2(zz[0]), p1 = fexp2(zz[1]);
                float p2 = fexp2(zz[2]), p3 = fexp2(zz[3]);
                up[qg][sub >> 1][(sub & 1) * 2 + 0] =
                    __builtin_bit_cast(unsigned int, __builtin_amdgcn_cvt_pkrtz(p0, p1));
                up[qg][sub >> 1][(sub & 1) * 2 + 1] =
                    __builtin_bit_cast(unsigned int, __builtin_amdgcn_cvt_pkrtz(p2, p3));
            }
        }
        f16x8 aP[2][2];
        aP[0][0] = __builtin_bit_cast(f16x8, up[0][0]);
        aP[0][1] = __builtin_bit_cast(f16x8, up[0][1]);
        aP[1][0] = __builtin_bit_cast(f16x8, up[1][0]);
        aP[1][1] = __builtin_bit_cast(f16x8, up[1][1]);

        #pragma unroll
        for (int dt = 0; dt < 4; dt++) {
            int row = dt * 16 + l16;
            f16x8 v0 = *(const f16x8*)&VTs[pb][(size_t)row * 64 + ((quad ^ sw) * 8)];
            f16x8 v1 = *(const f16x8*)&VTs[pb][(size_t)row * 64 + (((4 + quad) ^ sw) * 8)];
            #pragma unroll
            for (int qg = 0; qg < 2; qg++) {
                O[qg][dt] = MFMAH(aP[qg][0], v0, O[qg][dt]);
                O[qg][dt] = MFMAH(aP[qg][1], v1, O[qg][dt]);
            }
        }
        #pragma unroll
        for (int qg = 0; qg < 2; qg++) {
            Sd[qg] = MFMAH(aP[qg][0], onesv, Sd[qg]);
            Sd[qg] = MFMAH(aP[qg][1], onesv, Sd[qg]);
        }
        __syncthreads();
    }

    #pragma unroll
    for (int qg = 0; qg < 2; qg++) {
        float rd[4];
        #pragma unroll
        for (int r = 0; r < 4; r++) rd[r] = 1.0f / Sd[qg][r];
        #pragma unroll
        for (int dt = 0; dt < 4; dt++)
            #pragma unroll
            for (int r = 0; r < 4; r++) {
                float oo = O[qg][dt][r] * rd[r];
                int srow2 = qw + qg * 16 + quad * 4 + r;
                int col   = h * 64 + dt * 16 + l16;
                attnout[((size_t)(b * S_ + srow2)) * E_ + col] = f2bf(oo);
            }
    }
}

// ---------------------------------------------------------------------------
// Kernel 3: output projection. 64x128 tile, BK=32, dbuf async staging.
// grid=(8,64), block=256, fp32 out.  (round-10 config)
// ---------------------------------------------------------------------------
__global__ __launch_bounds__(256, 2) void oproj_kernel(
    const unsigned short* __restrict__ Aattn, const unsigned short* __restrict__ WoBf,
    const float* __restrict__ Wo, const float* __restrict__ bo, float* __restrict__ out)
{
    __shared__ __align__(16) unsigned short As[2][64 * 32];
    __shared__ __align__(16) unsigned short Bs[2][128 * 32];

    const int t = threadIdx.x;
    const int lane = t & 63, w = t >> 6;
    const int quad = lane >> 4, l16 = lane & 15;
    const int wm = (w & 1) * 32, wn = (w >> 1) * 64;
    const int rowBase = blockIdx.y * 64, nBase = blockIdx.x * 128;

    const int r0 = t >> 2;
    const int c4 = (t & 3) ^ (r0 & 3);
    const unsigned short* gA  = Aattn + (size_t)(rowBase + r0) * E_ + c4 * 8;
    const unsigned short* gBb = WoBf ? WoBf + (size_t)(nBase + r0) * E_ + c4 * 8 : nullptr;
    const float*          gBf = Wo + (size_t)(nBase + r0) * E_ + c4 * 8;

    f32x4 acc[2][4] = {};

    auto issue = [&](int kk, int pb) {
        gl16(gA + kk, &As[pb][(size_t)w * 512]);
        if (gBb) {
            unsigned short* dB = &Bs[pb][(size_t)w * 512];
            gl16(gBb + kk, dB);
            gl16(gBb + (size_t)64 * E_ + kk, dB + 2048);
        } else {
            const float* gp0 = gBf + kk;
            const float* gp1 = gBf + (size_t)64 * E_ + kk;
            f32x4 a0 = *(const f32x4*)gp0, a1 = *(const f32x4*)(gp0 + 4);
            f32x4 b0 = *(const f32x4*)gp1, b1 = *(const f32x4*)(gp1 + 4);
            *(s16x8*)&Bs[pb][(size_t)r0 * 32 + (t & 3) * 8]        = cvt8(a0, a1);
            *(s16x8*)&Bs[pb][(size_t)(r0 + 64) * 32 + (t & 3) * 8] = cvt8(b0, b1);
        }
    };

    issue(0, 0);
    __syncthreads();

    for (int s = 0; s < 32; s++) {
        const int pb = s & 1;
        if (s < 31) issue((s + 1) * 32, pb ^ 1);

        bf16x8 af[2], bfr[4];
        #pragma unroll
        for (int im = 0; im < 2; im++) {
            int r = wm + im * 16 + l16;
            af[im] = *(const bf16x8*)&As[pb][(size_t)r * 32 + ((quad ^ (l16 & 3)) * 8)];
        }
        #pragma unroll
        for (int in = 0; in < 4; in++) {
            int r = wn + in * 16 + l16;
            bfr[in] = *(const bf16x8*)&Bs[pb][(size_t)r * 32 + ((quad ^ (l16 & 3)) * 8)];
        }
        #pragma unroll
        for (int im = 0; im < 2; im++)
            #pragma unroll
            for (int in = 0; in < 4; in++)
                acc[im][in] = MFMA(af[im], bfr[in], acc[im][in]);
        __syncthreads();
    }

    #pragma unroll
    for (int im = 0; im < 2; im++)
      #pragma unroll
      for (int in = 0; in < 4; in++) {
          int col = nBase + wn + in * 16 + l16;
          float bb = bo[col];
          #pragma unroll
          for (int r = 0; r < 4; r++) {
              int row = rowBase + wm + im * 16 + quad * 4 + r;
              out[(size_t)row * E_ + col] = acc[im][in][r] + bb;
          }
      }
}

// ---------------------------------------------------------------------------
extern "C" void kernel_launch(void* const* d_in, const int* in_sizes, int n_in,
                              void* d_out, int out_size, void* d_ws, size_t ws_size,
                              hipStream_t stream) {
    const float* query = (const float*)d_in[0];
    const float* key_  = (const float*)d_in[1];
    const float* value = (const float*)d_in[2];
    const float* Wq = (const float*)d_in[3];
    const float* bq = (const float*)d_in[4];
    const float* Wk = (const float*)d_in[5];
    const float* bk = (const float*)d_in[6];
    const float* Wv = (const float*)d_in[7];
    const float* bv = (const float*)d_in[8];
    const float* Wo = (const float*)d_in[9];
    const float* bo = (const float*)d_in[10];

    unsigned short* ws      = (unsigned short*)d_ws;
    unsigned short* xv      = ws;                    // dead after qkv
    unsigned short* attnout = ws;                    // reuses xv region
    unsigned short* qkvout  = ws + PROJ_;            // 3*PROJ_
    size_t needW = (4 * PROJ_ + 4 * (size_t)E_ * E_) * 2;
    unsigned short* wbf = (ws_size >= needW) ? (ws + 4 * PROJ_) : nullptr;
    unsigned short* xq = (unsigned short*)d_out;     // scratch until oproj
    unsigned short* xk = xq + PROJ_;

    cvt_kernel<<<dim3(2048, wbf ? 7 : 3), 256, 0, stream>>>(
        query, key_, value, Wq, Wk, Wv, Wo, xq, xk, xv, wbf);
    qkv_kernel<<<dim3(8, 32, 3), 256, 0, stream>>>(
        xq, xk, xv, wbf, Wq, Wk, Wv, bq, bk, bv, qkvout);
    attn_kernel<<<dim3(32, 16), 256, 0, stream>>>(qkvout, attnout);
    oproj_kernel<<<dim3(8, 64), 256, 0, stream>>>(
        attnout, wbf ? wbf + 3 * (size_t)E_ * E_ : nullptr, Wo, bo, (float*)d_out);
}

// Round 2
// 222.501 us; speedup vs baseline: 1.0187x; 1.0187x over previous
//
#include <hip/hip_runtime.h>
#include <stdint.h>

#define B_ 2
#define S_ 2048
#define E_ 1024
#define H_ 16
#define D_ 64
#define M_ (B_*S_)
#define PROJ_ ((size_t)M_*E_)
#define HALF_W 128

typedef float    f32x4 __attribute__((ext_vector_type(4)));
typedef short    s16x4 __attribute__((ext_vector_type(4)));
typedef short    s16x8 __attribute__((ext_vector_type(8)));
typedef __bf16   bf16x8 __attribute__((ext_vector_type(8)));
typedef _Float16 f16x8 __attribute__((ext_vector_type(8)));
typedef unsigned int u32x4 __attribute__((ext_vector_type(4)));

typedef const __attribute__((address_space(1))) void* gas_t;
typedef __attribute__((address_space(3))) void*       las_t;

__device__ __forceinline__ void gl16(const void* g, void* l) {
    __builtin_amdgcn_global_load_lds((gas_t)g, (las_t)l, 16, 0, 0);
}

__device__ __forceinline__ f32x4 MFMA(bf16x8 a, bf16x8 b, f32x4 c) {
    return __builtin_amdgcn_mfma_f32_16x16x32_bf16(a, b, c, 0, 0, 0);
}
__device__ __forceinline__ f32x4 MFMAH(f16x8 a, f16x8 b, f32x4 c) {
    return __builtin_amdgcn_mfma_f32_16x16x32_f16(a, b, c, 0, 0, 0);
}

// raw v_exp_f32 — bypasses __ocml_exp2_f32's fixup path (args bounded here)
__device__ __forceinline__ float fexp2(float x) {
    return __builtin_amdgcn_exp2f(x);
}

__device__ __forceinline__ unsigned short f2bf(float f) {
    union { float f; unsigned int u; } x; x.f = f;
    unsigned int u = x.u + 0x7FFFu + ((x.u >> 16) & 1u);
    return (unsigned short)(u >> 16);
}

__device__ __forceinline__ s16x8 cvt8(f32x4 a, f32x4 b) {
    s16x8 h;
    h[0]=(short)f2bf(a[0]); h[1]=(short)f2bf(a[1]); h[2]=(short)f2bf(a[2]); h[3]=(short)f2bf(a[3]);
    h[4]=(short)f2bf(b[0]); h[5]=(short)f2bf(b[1]); h[6]=(short)f2bf(b[2]); h[7]=(short)f2bf(b[3]);
    return h;
}

// ---------------------------------------------------------------------------
// Kernel 0: fp32 -> bf16 converts (X inputs; W matrices when ws allows).
// ---------------------------------------------------------------------------
__global__ __launch_bounds__(256) void cvt_kernel(
    const float* __restrict__ q, const float* __restrict__ k, const float* __restrict__ v,
    const float* __restrict__ Wq, const float* __restrict__ Wk,
    const float* __restrict__ Wv, const float* __restrict__ Wo,
    unsigned short* __restrict__ xq, unsigned short* __restrict__ xk,
    unsigned short* __restrict__ xv, unsigned short* __restrict__ wbf)
{
    const int z = blockIdx.y;
    if (z >= 3 && blockIdx.x >= 512) return;
    const float* src; unsigned short* dst;
    switch (z) {
        case 0: src = q;  dst = xq; break;
        case 1: src = k;  dst = xk; break;
        case 2: src = v;  dst = xv; break;
        case 3: src = Wq; dst = wbf; break;
        case 4: src = Wk; dst = wbf + (size_t)E_*E_; break;
        case 5: src = Wv; dst = wbf + 2*(size_t)E_*E_; break;
        default: src = Wo; dst = wbf + 3*(size_t)E_*E_; break;
    }
    size_t i = ((size_t)blockIdx.x * 256 + threadIdx.x) * 8;
    f32x4 a = *(const f32x4*)(src + i);
    f32x4 c = *(const f32x4*)(src + i + 4);
    *(s16x8*)(dst + i) = cvt8(a, c);
}

// ---------------------------------------------------------------------------
// Kernel 1: QKV projections, operand-swapped (A=W rows, B=X rows).
// 128x128 tile, BK=32, LDS dbuf async staging, 1 barrier/step.
// K pre-scaled by 0.125*log2(e). V stored f16 in blocked (bh,kb,d,slot)
// layout. grid=(8,32,3), block=256.  (round-10 config: best measured)
// ---------------------------------------------------------------------------
__global__ __launch_bounds__(256, 3) void qkv_kernel(
    const unsigned short* __restrict__ xq, const unsigned short* __restrict__ xk,
    const unsigned short* __restrict__ xv,
    const unsigned short* __restrict__ wbf,
    const float* __restrict__ Wq, const float* __restrict__ Wk, const float* __restrict__ Wv,
    const float* __restrict__ bq, const float* __restrict__ bk, const float* __restrict__ bv,
    unsigned short* __restrict__ qkvout)
{
    const int z = blockIdx.z;
    const unsigned short* X  = (z==0) ? xq : (z==1) ? xk : xv;
    const float*          Wf = (z==0) ? Wq : (z==1) ? Wk : Wv;
    const float*        bias = (z==0) ? bq : (z==1) ? bk : bv;
    const unsigned short* Wb = wbf ? (wbf + (size_t)z * E_ * E_) : nullptr;
    unsigned short* dst = qkvout + (size_t)z * PROJ_;

    __shared__ __align__(16) unsigned short As[2][128 * 32];   // W tile
    __shared__ __align__(16) unsigned short Bs[2][128 * 32];   // X tile

    const int t = threadIdx.x;
    const int lane = t & 63, w = t >> 6;
    const int quad = lane >> 4, l16 = lane & 15;
    const int wo = (w & 1) * 64, wsb = (w >> 1) * 64;
    const int oBase = blockIdx.x * 128, sBase = blockIdx.y * 128;

    const int r0 = t >> 2;
    const int c4 = (t & 3) ^ (r0 & 3);
    const unsigned short* gX  = X + (size_t)(sBase + r0) * E_ + c4 * 8;
    const unsigned short* gWb = Wb ? Wb + (size_t)(oBase + r0) * E_ + c4 * 8 : nullptr;
    const float*          gWf = Wf + (size_t)(oBase + r0) * E_ + c4 * 8;

    f32x4 acc[4][4] = {};   // [io][is]

    auto issue = [&](int kk, int pb) {
        unsigned short* dB = &Bs[pb][(size_t)w * 512];
        gl16(gX + kk, dB);
        gl16(gX + (size_t)64 * E_ + kk, dB + 2048);
        if (gWb) {
            unsigned short* dA = &As[pb][(size_t)w * 512];
            gl16(gWb + kk, dA);
            gl16(gWb + (size_t)64 * E_ + kk, dA + 2048);
        } else {
            const float* gp0 = gWf + kk;
            const float* gp1 = gWf + (size_t)64 * E_ + kk;
            f32x4 a0 = *(const f32x4*)gp0, a1 = *(const f32x4*)(gp0 + 4);
            f32x4 b0 = *(const f32x4*)gp1, b1 = *(const f32x4*)(gp1 + 4);
            *(s16x8*)&As[pb][(size_t)r0 * 32 + (t & 3) * 8]        = cvt8(a0, a1);
            *(s16x8*)&As[pb][(size_t)(r0 + 64) * 32 + (t & 3) * 8] = cvt8(b0, b1);
        }
    };

    issue(0, 0);
    __syncthreads();

    for (int s = 0; s < 32; s++) {
        const int pb = s & 1;
        if (s < 31) issue((s + 1) * 32, pb ^ 1);

        bf16x8 af[4], bfr[4];
        #pragma unroll
        for (int io = 0; io < 4; io++) {
            int r = wo + io * 16 + l16;
            af[io] = *(const bf16x8*)&As[pb][(size_t)r * 32 + ((quad ^ (l16 & 3)) * 8)];
        }
        #pragma unroll
        for (int is = 0; is < 4; is++) {
            int r = wsb + is * 16 + l16;
            bfr[is] = *(const bf16x8*)&Bs[pb][(size_t)r * 32 + ((quad ^ (l16 & 3)) * 8)];
        }
        #pragma unroll
        for (int io = 0; io < 4; io++)
            #pragma unroll
            for (int is = 0; is < 4; is++)
                acc[io][is] = MFMA(af[io], bfr[is], acc[io][is]);
        __syncthreads();
    }

    const float KSCL = 0.1803368801111204f;   // 0.125 * log2(e)
    #pragma unroll
    for (int is = 0; is < 4; is++) {
        int sg = sBase + wsb + is * 16 + l16;     // b*S + s
        int b = sg >> 11, sg2 = sg & 2047;
        int k6 = sg2 & 63;
        int slot = ((k6 >> 5) & 1) * 32 + ((k6 >> 2) & 3) * 8
                 + ((k6 >> 4) & 1) * 4 + (k6 & 3);
        #pragma unroll
        for (int io = 0; io < 4; io++) {
            int ocol0 = oBase + wo + io * 16 + quad * 4;
            f32x4 bias4 = *(const f32x4*)&bias[ocol0];
            int h = ocol0 >> 6, d0 = ocol0 & 63;
            size_t base = ((size_t)(b * H_ + h)) * ((size_t)S_ * D_);
            if (z == 0) {
                s16x4 h4;
                #pragma unroll
                for (int r = 0; r < 4; r++) h4[r] = (short)f2bf(acc[io][is][r] + bias4[r]);
                *(s16x4*)&dst[base + (size_t)sg2 * D_ + d0] = h4;
            } else if (z == 1) {
                s16x4 h4;
                #pragma unroll
                for (int r = 0; r < 4; r++)
                    h4[r] = (short)f2bf((acc[io][is][r] + bias4[r]) * KSCL);
                *(s16x4*)&dst[base + (size_t)sg2 * D_ + d0] = h4;
            } else {
                size_t vb = base + (size_t)(sg2 >> 6) * 4096 + (size_t)d0 * 64 + slot;
                #pragma unroll
                for (int r = 0; r < 4; r++) {
                    _Float16 hv = (_Float16)(acc[io][is][r] + bias4[r]);
                    dst[vb + (size_t)r * 64] = __builtin_bit_cast(unsigned short, hv);
                }
            }
        }
    }
}

// ---------------------------------------------------------------------------
// Kernel 2: fused attention. grid=(32 bh, 32 qtile), block=256 (4 waves).
// K-SPLIT wave layout: wave w -> (qh = w&1, hw = w>>1). Each wave computes
// 32 q rows x its 32-key half per 64-key tile: per-wave LDS reads per tile
// drop 16 -> 8 ds_read_b128 (round-1 showed LDS reuse must come WITHOUT
// shrinking the grid: 512 blocks = 2 blocks/CU tanked occupancy to 17%).
// Additive mask folded into MFMA C-init (wave-uniform class per 16x16
// subtile; per-elem cndmask only at d=+-128 boundary). Non-normalized
// online accumulation (O, Sigma-p via ones-MFMA) lets k-half partials
// combine by a single LDS exchange + add at block end.
// ---------------------------------------------------------------------------
__global__ __launch_bounds__(256, 4) void attn_kernel(
    const unsigned short* __restrict__ qkvout, unsigned short* __restrict__ attnout)
{
    const int bh = blockIdx.x, b = bh >> 4, h = bh & 15;
    const int qbase = blockIdx.y * 64;
    const int t = threadIdx.x, w = t >> 6, lane = t & 63;
    const int quad = lane >> 4, l16 = lane & 15;
    const int qh = w & 1;          // q-half: waves 0,2 -> rows 0..31; 1,3 -> 32..63
    const int hw = w >> 1;         // k-half: waves 0,1 -> keys 0..31; 2,3 -> 32..63

    const unsigned short* qgp = qkvout + (size_t)bh * (S_ * D_);
    const unsigned short* kg = qkvout + PROJ_ + (size_t)bh * (S_ * D_);
    const unsigned short* vT = qkvout + 2 * PROJ_ + (size_t)bh * (S_ * D_);

    __shared__ __align__(16) unsigned short Ks [2][64 * 64];
    __shared__ __align__(16) unsigned short VTs[2][64 * 64];

    const int qw = qbase + qh * 32;     // wave's first q row
    bf16x8 aq[2][2];
    #pragma unroll
    for (int qg = 0; qg < 2; qg++) {
        int qi = qw + qg * 16 + l16;
        aq[qg][0] = *(const bf16x8*)&qgp[(size_t)qi * 64 + quad * 8];
        aq[qg][1] = *(const bf16x8*)&qgp[(size_t)qi * 64 + 32 + quad * 8];
    }

    f32x4 O[2][4] = {};     // [qg][dt] partial over this wave's k-half
    f32x4 Sd[2] = {};       // partial softmax denominators

    const int r0 = t >> 3;
    const int ch = ((t & 7) ^ (r0 & 7)) * 8;

    f16x8 onesv;
    #pragma unroll
    for (int j = 0; j < 8; j++) onesv[j] = (_Float16)1.0f;

    const float LOG2E = 1.44269504089f;
    const f32x4 one4 = {LOG2E, LOG2E, LOG2E, LOG2E};
    const f32x4 zero4 = {};

    auto issue = [&](int kt, int pb) {
        unsigned short* dK = &Ks [pb][(size_t)w * 512];
        unsigned short* dV = &VTs[pb][(size_t)w * 512];
        gl16(kg + (size_t)(kt + r0) * 64 + ch,      dK);
        gl16(kg + (size_t)(kt + r0 + 32) * 64 + ch, dK + 2048);
        gl16(vT + (size_t)(kt + r0) * 64 + ch,      dV);
        gl16(vT + (size_t)(kt + r0 + 32) * 64 + ch, dV + 2048);
    };

    issue(0, 0);
    __syncthreads();

    const int sw = l16 & 7;
    const int vch = (((hw * 4) + quad) ^ sw) * 8;   // this wave's V k-chunk

    #pragma unroll 2
    for (int s = 0; s < 32; s++) {
        const int pb = s & 1;
        const int kt = s * 64;
        if (s < 31) issue(kt + 64, pb ^ 1);

        // P for this wave's 32 keys: pp[qg][sub], keys kt+hw*32+sub*16+quad*4+r
        f32x4 pp[2][2];
        #pragma unroll
        for (int sub = 0; sub < 2; sub++) {
            int row = hw * 32 + sub * 16 + l16;
            bf16x8 bk0 = *(const bf16x8*)&Ks[pb][(size_t)row * 64 + ((quad ^ sw) * 8)];
            bf16x8 bk1 = *(const bf16x8*)&Ks[pb][(size_t)row * 64 + (((4 + quad) ^ sw) * 8)];
            #pragma unroll
            for (int qg = 0; qg < 2; qg++) {
                // 16q x 16k subtile class: d = Q0 - J0; di = q-j in [d-15, d+15]
                int d = qw + qg * 16 - (kt + hw * 32 + sub * 16);
                f32x4 ci;
                if (d >= -112 && d <= 112) {
                    ci = zero4;                         // fully in-window: mask 0
                } else if (d >= 144 || d <= -144) {
                    ci = one4;                          // fully outside: mask +1
                } else {                                // boundary (d = +-128)
                    int jb = kt + hw * 32 + sub * 16 + quad * 4;
                    int qi = qw + qg * 16 + l16;
                    #pragma unroll
                    for (int r = 0; r < 4; r++) {
                        int di = qi - (jb + r); di = di < 0 ? -di : di;
                        ci[r] = (di <= HALF_W) ? 0.f : LOG2E;
                    }
                }
                f32x4 zz = MFMA(bk0, aq[qg][0], ci);
                zz = MFMA(bk1, aq[qg][1], zz);
                pp[qg][sub][0] = fexp2(zz[0]); pp[qg][sub][1] = fexp2(zz[1]);
                pp[qg][sub][2] = fexp2(zz[2]); pp[qg][sub][3] = fexp2(zz[3]);
            }
        }

        f16x8 aP[2];
        #pragma unroll
        for (int qg = 0; qg < 2; qg++) {
            u32x4 up;
            up[0] = __builtin_bit_cast(unsigned int, __builtin_amdgcn_cvt_pkrtz(pp[qg][0][0], pp[qg][0][1]));
            up[1] = __builtin_bit_cast(unsigned int, __builtin_amdgcn_cvt_pkrtz(pp[qg][0][2], pp[qg][0][3]));
            up[2] = __builtin_bit_cast(unsigned int, __builtin_amdgcn_cvt_pkrtz(pp[qg][1][0], pp[qg][1][1]));
            up[3] = __builtin_bit_cast(unsigned int, __builtin_amdgcn_cvt_pkrtz(pp[qg][1][2], pp[qg][1][3]));
            aP[qg] = __builtin_bit_cast(f16x8, up);
        }

        #pragma unroll
        for (int dt = 0; dt < 4; dt++) {
            int row = dt * 16 + l16;
            f16x8 v = *(const f16x8*)&VTs[pb][(size_t)row * 64 + vch];
            O[0][dt] = MFMAH(aP[0], v, O[0][dt]);
            O[1][dt] = MFMAH(aP[1], v, O[1][dt]);
        }
        Sd[0] = MFMAH(aP[0], onesv, Sd[0]);
        Sd[1] = MFMAH(aP[1], onesv, Sd[1]);
        __syncthreads();
    }

    // k-half combine: hw=1 waves park partials in LDS; hw=0 waves add + write.
    float* LsO = (float*)&Ks[0][0];     // 8 chunks x 128 lanes x f32x4 = 16 KB
    float* LsS = (float*)&VTs[0][0];    // 2 chunks x 128 lanes x f32x4 = 4 KB
    if (hw == 1) {
        #pragma unroll
        for (int qg = 0; qg < 2; qg++) {
            #pragma unroll
            for (int dt = 0; dt < 4; dt++)
                *(f32x4*)&LsO[(((qg * 4 + dt) * 128) + qh * 64 + lane) * 4] = O[qg][dt];
            *(f32x4*)&LsS[((qg * 128) + qh * 64 + lane) * 4] = Sd[qg];
        }
    }
    __syncthreads();
    if (hw == 0) {
        #pragma unroll
        for (int qg = 0; qg < 2; qg++) {
            f32x4 st = Sd[qg] + *(const f32x4*)&LsS[((qg * 128) + qh * 64 + lane) * 4];
            float rd[4];
            #pragma unroll
            for (int r = 0; r < 4; r++) rd[r] = 1.0f / st[r];
            #pragma unroll
            for (int dt = 0; dt < 4; dt++) {
                f32x4 ot = O[qg][dt]
                    + *(const f32x4*)&LsO[(((qg * 4 + dt) * 128) + qh * 64 + lane) * 4];
                #pragma unroll
                for (int r = 0; r < 4; r++) {
                    float oo = ot[r] * rd[r];
                    int srow2 = qw + qg * 16 + quad * 4 + r;
                    int col   = h * 64 + dt * 16 + l16;
                    attnout[((size_t)(b * S_ + srow2)) * E_ + col] = f2bf(oo);
                }
            }
        }
    }
}

// ---------------------------------------------------------------------------
// Kernel 3: output projection. 64x128 tile, BK=32, dbuf async staging.
// grid=(8,64), block=256, fp32 out.  (round-10 config)
// ---------------------------------------------------------------------------
__global__ __launch_bounds__(256, 2) void oproj_kernel(
    const unsigned short* __restrict__ Aattn, const unsigned short* __restrict__ WoBf,
    const float* __restrict__ Wo, const float* __restrict__ bo, float* __restrict__ out)
{
    __shared__ __align__(16) unsigned short As[2][64 * 32];
    __shared__ __align__(16) unsigned short Bs[2][128 * 32];

    const int t = threadIdx.x;
    const int lane = t & 63, w = t >> 6;
    const int quad = lane >> 4, l16 = lane & 15;
    const int wm = (w & 1) * 32, wn = (w >> 1) * 64;
    const int rowBase = blockIdx.y * 64, nBase = blockIdx.x * 128;

    const int r0 = t >> 2;
    const int c4 = (t & 3) ^ (r0 & 3);
    const unsigned short* gA  = Aattn + (size_t)(rowBase + r0) * E_ + c4 * 8;
    const unsigned short* gBb = WoBf ? WoBf + (size_t)(nBase + r0) * E_ + c4 * 8 : nullptr;
    const float*          gBf = Wo + (size_t)(nBase + r0) * E_ + c4 * 8;

    f32x4 acc[2][4] = {};

    auto issue = [&](int kk, int pb) {
        gl16(gA + kk, &As[pb][(size_t)w * 512]);
        if (gBb) {
            unsigned short* dB = &Bs[pb][(size_t)w * 512];
            gl16(gBb + kk, dB);
            gl16(gBb + (size_t)64 * E_ + kk, dB + 2048);
        } else {
            const float* gp0 = gBf + kk;
            const float* gp1 = gBf + (size_t)64 * E_ + kk;
            f32x4 a0 = *(const f32x4*)gp0, a1 = *(const f32x4*)(gp0 + 4);
            f32x4 b0 = *(const f32x4*)gp1, b1 = *(const f32x4*)(gp1 + 4);
            *(s16x8*)&Bs[pb][(size_t)r0 * 32 + (t & 3) * 8]        = cvt8(a0, a1);
            *(s16x8*)&Bs[pb][(size_t)(r0 + 64) * 32 + (t & 3) * 8] = cvt8(b0, b1);
        }
    };

    issue(0, 0);
    __syncthreads();

    for (int s = 0; s < 32; s++) {
        const int pb = s & 1;
        if (s < 31) issue((s + 1) * 32, pb ^ 1);

        bf16x8 af[2], bfr[4];
        #pragma unroll
        for (int im = 0; im < 2; im++) {
            int r = wm + im * 16 + l16;
            af[im] = *(const bf16x8*)&As[pb][(size_t)r * 32 + ((quad ^ (l16 & 3)) * 8)];
        }
        #pragma unroll
        for (int in = 0; in < 4; in++) {
            int r = wn + in * 16 + l16;
            bfr[in] = *(const bf16x8*)&Bs[pb][(size_t)r * 32 + ((quad ^ (l16 & 3)) * 8)];
        }
        #pragma unroll
        for (int im = 0; im < 2; im++)
            #pragma unroll
            for (int in = 0; in < 4; in++)
                acc[im][in] = MFMA(af[im], bfr[in], acc[im][in]);
        __syncthreads();
    }

    #pragma unroll
    for (int im = 0; im < 2; im++)
      #pragma unroll
      for (int in = 0; in < 4; in++) {
          int col = nBase + wn + in * 16 + l16;
          float bb = bo[col];
          #pragma unroll
          for (int r = 0; r < 4; r++) {
              int row = rowBase + wm + im * 16 + quad * 4 + r;
              out[(size_t)row * E_ + col] = acc[im][in][r] + bb;
          }
      }
}

// ---------------------------------------------------------------------------
extern "C" void kernel_launch(void* const* d_in, const int* in_sizes, int n_in,
                              void* d_out, int out_size, void* d_ws, size_t ws_size,
                              hipStream_t stream) {
    const float* query = (const float*)d_in[0];
    const float* key_  = (const float*)d_in[1];
    const float* value = (const float*)d_in[2];
    const float* Wq = (const float*)d_in[3];
    const float* bq = (const float*)d_in[4];
    const float* Wk = (const float*)d_in[5];
    const float* bk = (const float*)d_in[6];
    const float* Wv = (const float*)d_in[7];
    const float* bv = (const float*)d_in[8];
    const float* Wo = (const float*)d_in[9];
    const float* bo = (const float*)d_in[10];

    unsigned short* ws      = (unsigned short*)d_ws;
    unsigned short* xv      = ws;                    // dead after qkv
    unsigned short* attnout = ws;                    // reuses xv region
    unsigned short* qkvout  = ws + PROJ_;            // 3*PROJ_
    size_t needW = (4 * PROJ_ + 4 * (size_t)E_ * E_) * 2;
    unsigned short* wbf = (ws_size >= needW) ? (ws + 4 * PROJ_) : nullptr;
    unsigned short* xq = (unsigned short*)d_out;     // scratch until oproj
    unsigned short* xk = xq + PROJ_;

    cvt_kernel<<<dim3(2048, wbf ? 7 : 3), 256, 0, stream>>>(
        query, key_, value, Wq, Wk, Wv, Wo, xq, xk, xv, wbf);
    qkv_kernel<<<dim3(8, 32, 3), 256, 0, stream>>>(
        xq, xk, xv, wbf, Wq, Wk, Wv, bq, bk, bv, qkvout);
    attn_kernel<<<dim3(32, 32), 256, 0, stream>>>(qkvout, attnout);
    oproj_kernel<<<dim3(8, 64), 256, 0, stream>>>(
        attnout, wbf ? wbf + 3 * (size_t)E_ * E_ : nullptr, Wo, bo, (float*)d_out);
}